// Round 4
// baseline (1372.562 us; speedup 1.0000x reference)
//
#include <hip/hip_runtime.h>

// WaveNet (nsynth batch-folding) on MI355X — single persistent kernel.
// Stream identity: batch-folding dilation == dilated conv over one 8192-sample
// stream, j = l*2 + n; fold-d taps at j +- 2d, zero-pad at stream ends.
// Net = init -> iskip -> 30x {K3 conv (G,F) -> gate -> 1x1 thru/skip} -> final,
// all on H[8192][256]; bf16 MFMA, fp32 masters for H and S.
//
// v4: ONE kernel, 256 blocks (1/CU) x 512 threads, hand-rolled grid barrier
// between layers (device-scope atomics; release = L2 writeback, acquire =
// L2 inv; working set ~70MB stays in L3). B weights: global_load_lds DMA,
// 3-buffer ring, depth-2 counted vmcnt(8) (never 0 in the loop). Epilogue
// operands preloaded at layer start; phase-2 chunks issued during phase-1
// tail and fly across the res barriers; final GEMM reads S from LDS.

#define TS 8192
#define NL 30
#define NBLK 256

typedef __attribute__((ext_vector_type(8))) short bf16x8;
typedef __attribute__((ext_vector_type(4))) float f32x4;

__device__ __forceinline__ unsigned short f2bf(float f) {
    union { float f; unsigned int u; } v; v.f = f;
    unsigned int u = v.u;
    u += 0x7fffu + ((u >> 16) & 1u);   // RNE
    return (unsigned short)(u >> 16);
}

__device__ __forceinline__ void gload_lds16(const void* g, void* l) {
    __builtin_amdgcn_global_load_lds(
        (const __attribute__((address_space(1))) void*)g,
        (__attribute__((address_space(3))) void*)l, 16, 0, 0);
}

#define VMW8()  asm volatile("s_waitcnt vmcnt(8)" ::: "memory")
#define VMW4()  asm volatile("s_waitcnt vmcnt(4)" ::: "memory")
#define VMW0()  asm volatile("s_waitcnt vmcnt(0)" ::: "memory")
#define LGKM0() asm volatile("s_waitcnt lgkmcnt(0)" ::: "memory")
#define SBAR()  __builtin_amdgcn_s_barrier()

__device__ __forceinline__ int swz_jb(int bid) {   // XCD-chunked j-tile map
    return ((bid & 7) << 5) | (bid >> 3);
}

// ---------------------------------------------------------------------------
// Weight prep: fp32 -> bf16 with layout transforms.
// Wgf[k][t][o][ci], o in [0,512): 0..255 gate, 256..511 feat (tap t split out)
// Wts[k][o][ci],    o in [0,512): 0..255 thru, 256..511 skip
// ---------------------------------------------------------------------------
__global__ void prep_weights_kernel(
    const float* __restrict__ gw, const float* __restrict__ fw,
    const float* __restrict__ tw, const float* __restrict__ sw,
    const float* __restrict__ iw, const float* __restrict__ fnw,
    unsigned short* __restrict__ Wgf, unsigned short* __restrict__ Wts,
    unsigned short* __restrict__ Wib, unsigned short* __restrict__ Wfb)
{
    const int idx = blockIdx.x * blockDim.x + threadIdx.x;
    const int stride = gridDim.x * blockDim.x;
    const int n_gf = NL * 3 * 512 * 256;
    for (int i = idx; i < n_gf; i += stride) {
        int ci = i & 255;
        int o  = (i >> 8) & 511;
        int r  = i >> 17;      // k*3 + t
        int t  = r % 3;
        int k  = r / 3;
        float v = (o < 256) ? gw[((k * 256 + o) * 256 + ci) * 3 + t]
                            : fw[((k * 256 + (o - 256)) * 256 + ci) * 3 + t];
        Wgf[i] = f2bf(v);
    }
    const int n_ts = NL * 512 * 256;
    for (int i = idx; i < n_ts; i += stride) {
        int ci = i & 255;
        int o  = (i >> 8) & 511;
        int k  = i >> 17;
        float v = (o < 256) ? tw[(k * 256 + o) * 256 + ci]
                            : sw[(k * 256 + (o - 256)) * 256 + ci];
        Wts[i] = f2bf(v);
    }
    for (int i = idx; i < 256 * 256; i += stride) Wib[i] = f2bf(iw[i]);
    for (int i = idx; i < 256 * 256; i += stride) Wfb[i] = f2bf(fnw[i]);
}

// ---------------------------------------------------------------------------
// Grid barrier: monotonic counter, release/acquire at agent scope.
// Release flushes this XCD's dirty L2 to L3; acquire invalidates L1/L2 so
// halo reads see other XCDs' writes. DMA weight loads are never stale, so
// in-flight global_load_lds crossing the inv is safe.
// ---------------------------------------------------------------------------
__device__ __forceinline__ void grid_barrier(unsigned* cnt, unsigned target, int tid) {
    __syncthreads();   // all waves' stores accepted by L2 (vmcnt drained)
    if (tid == 0) {
        __hip_atomic_fetch_add(cnt, 1u, __ATOMIC_RELEASE, __HIP_MEMORY_SCOPE_AGENT);
        while (__hip_atomic_load(cnt, __ATOMIC_RELAXED, __HIP_MEMORY_SCOPE_AGENT) < target)
            __builtin_amdgcn_s_sleep(2);
        (void)__hip_atomic_load(cnt, __ATOMIC_ACQUIRE, __HIP_MEMORY_SCOPE_AGENT);
    }
    __syncthreads();
}

// ---------------------------------------------------------------------------
// B-chunk staging (v2 pattern): chunk c in [0,32): c<24 -> Wgf tap t=c>>3,
// kc=c&7 (gate rows 32w.., feat rows 256+32w..); c>=24 -> Wts kc=c-24
// (rows 64w..). Per-wave private slice, ring of 3 x 4KB. Linear LDS dest,
// 16B-slot XOR pre-swizzle on the SOURCE, undone at read time.
// ---------------------------------------------------------------------------
__device__ __forceinline__ void stage_chunk(
    const unsigned short* __restrict__ Wgf_k,
    const unsigned short* __restrict__ Wts_k,
    unsigned short* B_lds, int c, int w, int lane)
{
    const int buf  = c % 3;
    const int rsub = lane >> 2;                       // 0..15
    const int slot = (lane & 3) ^ ((lane >> 3) & 3);  // pre-swizzled src slot
    unsigned short* dst = B_lds + w * 6144 + buf * 2048;
    if (c < 24) {
        const int t = c >> 3, kc = c & 7;
        const unsigned short* Wb = Wgf_k + (t * 512 + 32 * w) * 256 + kc * 32 + slot * 8;
        #pragma unroll
        for (int q = 0; q < 4; ++q) {
            const int r_loc = q * 16 + rsub;                   // 0..63
            const int grow  = (q < 2) ? r_loc : (224 + r_loc); // feat at +256
            gload_lds16(Wb + grow * 256, dst + q * 512);
        }
    } else {
        const int kc = c - 24;
        const unsigned short* Wb = Wts_k + (64 * w) * 256 + kc * 32 + slot * 8;
        #pragma unroll
        for (int q = 0; q < 4; ++q)
            gload_lds16(Wb + (q * 16 + rsub) * 256, dst + q * 512);
    }
}

// read B fragment: local row r (0..63), k-quarter krow (0..3)
__device__ __forceinline__ bf16x8 bread(const unsigned short* Bw, int r, int krow)
{
    const int slot = krow ^ ((r >> 1) & 3);
    return *(const bf16x8*)(Bw + r * 32 + slot * 8);
}

// ---------------------------------------------------------------------------
__global__ __launch_bounds__(512, 2)
void wavenet_kernel(const float* __restrict__ x,
                    const float* __restrict__ init_w,
                    const float* __restrict__ init_b,
                    const unsigned short* __restrict__ Wib,
                    const float* __restrict__ ib,
                    const unsigned short* __restrict__ Wgf,
                    const unsigned short* __restrict__ Wts,
                    const float* __restrict__ gbA,
                    const float* __restrict__ fbA,
                    const unsigned short* __restrict__ Wfb,
                    const float* __restrict__ fbias,
                    float* __restrict__ Hf0, float* __restrict__ Hf1,
                    unsigned short* __restrict__ Hb0, unsigned short* __restrict__ Hb1,
                    float* __restrict__ Sf,
                    float* __restrict__ out,
                    unsigned* __restrict__ counter)
{
    __shared__ __align__(16) unsigned short A_lds[3 * 32 * 256];   // 48 KB (tap0 doubles as res/S buffer)
    __shared__ __align__(16) unsigned short B_lds[8 * 3 * 2048];   // 96 KB

    const int tid  = threadIdx.x;
    const int lane = tid & 63;
    const int w    = tid >> 6;
    const int j0   = swz_jb(blockIdx.x) * 32;
    const int arow = lane & 15;
    const int krow = lane >> 4;
    const int aswz = (arow & 7) << 4;
    const int cg0  = w * 32;
    const int c0   = w * 64;

    // ================= init conv: H0 rows j0..j0+31 =================
    for (int idx = tid; idx < 32 * 256; idx += 512) {
        const int row = idx >> 8, co = idx & 255, j = j0 + row;
        float acc = init_b[co];
        #pragma unroll
        for (int t = 0; t < 3; ++t) {
            const int i = j + 2 * t - 2;
            if (i >= 0 && i < TS)
                acc += init_w[co * 3 + t] * x[(i & 1) * 4096 + (i >> 1)];
        }
        Hf0[(j << 8) + co] = acc;
        Hb0[(j << 8) + co] = f2bf(acc);
    }

    unsigned target = NBLK;
    grid_barrier(counter, target, tid);

    const unsigned short* Hb_in = Hb0;  const float* Hf_in = Hf0;
    unsigned short* Hb_out = Hb1;       float* Hf_out = Hf1;

    for (int k = 0; k < NL; ++k) {
        const int d = 2 << (k % 10);   // stream dilation = 2 * 2^(k%10)
        const unsigned short* Wgf_k = Wgf + (size_t)k * 3 * 512 * 256;
        const unsigned short* Wts_k = Wts + (size_t)k * 512 * 256;
        const float* gb = gbA + k * 256;
        const float* fb = fbA + k * 256;

        const float* Pbase = (w < 4) ? Hf_in : Sf;
        const int colb = (w < 4) ? c0 : (c0 - 256);
        float hin[2][4][4];

        if (k > 0) {   // epilogue operand preload, earliest (latency hides under A-stage)
            #pragma unroll
            for (int rt = 0; rt < 2; ++rt)
                #pragma unroll
                for (int fc = 0; fc < 4; ++fc)
                    #pragma unroll
                    for (int i = 0; i < 4; ++i) {
                        const int row = rt * 16 + krow * 4 + i;
                        hin[rt][fc][i] = Pbase[((j0 + row) << 8) + colb + fc * 16 + arow];
                    }
        }

        // ---- A-stage: 3 taps x 32 rows x 256 ch, row-XOR swizzle ----
        for (int cc = tid; cc < 3 * 32 * 32; cc += 512) {
            const int c16 = cc & 31;
            const int m   = (cc >> 5) & 31;
            const int t   = cc >> 10;
            const int r   = j0 + m + (t - 1) * d;
            uint4 v = make_uint4(0u, 0u, 0u, 0u);
            if (r >= 0 && r < TS)
                v = *(const uint4*)(Hb_in + (r << 8) + (c16 << 3));
            const int sb = (c16 << 4) ^ ((m & 7) << 4);
            *(uint4*)(A_lds + ((t * 32 + m) << 8) + (sb >> 1)) = v;
        }

        if (k == 0) {
            LGKM0(); SBAR();   // A visible
            // ---- iskip: S = ib + H0 @ Wib^T (A from tap1, B direct global) ----
            f32x4 sacc[2][2];
            #pragma unroll
            for (int rt = 0; rt < 2; ++rt)
                #pragma unroll
                for (int fc = 0; fc < 2; ++fc) {
                    const float b = ib[cg0 + fc * 16 + arow];
                    sacc[rt][fc] = (f32x4){b, b, b, b};
                }
            #pragma unroll
            for (int kc = 0; kc < 8; ++kc) {
                const int aoff = ((kc * 64 + krow * 16) ^ aswz) >> 1;
                const bf16x8 a0 = *(const bf16x8*)(A_lds + ((32 + arow) << 8) + aoff);
                const bf16x8 a1 = *(const bf16x8*)(A_lds + ((48 + arow) << 8) + aoff);
                const int koff = kc * 32 + krow * 8;
                const bf16x8 b0 = *(const bf16x8*)(Wib + ((cg0 + arow) << 8) + koff);
                const bf16x8 b1 = *(const bf16x8*)(Wib + ((cg0 + 16 + arow) << 8) + koff);
                sacc[0][0] = __builtin_amdgcn_mfma_f32_16x16x32_bf16(a0, b0, sacc[0][0], 0, 0, 0);
                sacc[1][0] = __builtin_amdgcn_mfma_f32_16x16x32_bf16(a1, b0, sacc[1][0], 0, 0, 0);
                sacc[0][1] = __builtin_amdgcn_mfma_f32_16x16x32_bf16(a0, b1, sacc[0][1], 0, 0, 0);
                sacc[1][1] = __builtin_amdgcn_mfma_f32_16x16x32_bf16(a1, b1, sacc[1][1], 0, 0, 0);
            }
            #pragma unroll
            for (int rt = 0; rt < 2; ++rt)
                #pragma unroll
                for (int fc = 0; fc < 2; ++fc)
                    #pragma unroll
                    for (int i = 0; i < 4; ++i) {
                        const int row = rt * 16 + krow * 4 + i;
                        Sf[((j0 + row) << 8) + cg0 + fc * 16 + arow] = sacc[rt][fc][i];
                    }
            VMW0(); SBAR();    // S visible to all waves of this block
            #pragma unroll
            for (int rt = 0; rt < 2; ++rt)
                #pragma unroll
                for (int fc = 0; fc < 4; ++fc)
                    #pragma unroll
                    for (int i = 0; i < 4; ++i) {
                        const int row = rt * 16 + krow * 4 + i;
                        hin[rt][fc][i] = Pbase[((j0 + row) << 8) + colb + fc * 16 + arow];
                    }
            stage_chunk(Wgf_k, Wts_k, B_lds, 0, w, lane);
            stage_chunk(Wgf_k, Wts_k, B_lds, 1, w, lane);
        } else {
            stage_chunk(Wgf_k, Wts_k, B_lds, 0, w, lane);
            stage_chunk(Wgf_k, Wts_k, B_lds, 1, w, lane);
            LGKM0(); SBAR();   // A visible (B chunks keep flying)
        }

        // ---- phase 1: 24 chunks, ring-3, depth-2 counted vmcnt ----
        f32x4 accG[2][2], accF[2][2];
        #pragma unroll
        for (int rt = 0; rt < 2; ++rt)
            #pragma unroll
            for (int fc = 0; fc < 2; ++fc) {
                const float g = gb[cg0 + fc * 16 + arow];
                const float f = fb[cg0 + fc * 16 + arow];
                accG[rt][fc] = (f32x4){g, g, g, g};
                accF[rt][fc] = (f32x4){f, f, f, f};
            }

        #pragma unroll
        for (int c = 0; c < 24; ++c) {
            stage_chunk(Wgf_k, Wts_k, B_lds, c + 2, w, lane);   // c=22,23 issue Wts chunks 24,25
            VMW8();                                             // chunk c landed
            const int t = c >> 3, kc = c & 7;
            const int aoff = ((kc * 64 + krow * 16) ^ aswz) >> 1;
            const unsigned short* At = A_lds + ((t * 32 + arow) << 8);
            const bf16x8 a0 = *(const bf16x8*)(At + aoff);
            const bf16x8 a1 = *(const bf16x8*)(At + (16 << 8) + aoff);
            const unsigned short* Bw = B_lds + w * 6144 + (c % 3) * 2048;
            const bf16x8 bg0 = bread(Bw, arow, krow);
            const bf16x8 bg1 = bread(Bw, 16 + arow, krow);
            const bf16x8 bf0 = bread(Bw, 32 + arow, krow);
            const bf16x8 bf1 = bread(Bw, 48 + arow, krow);
            accG[0][0] = __builtin_amdgcn_mfma_f32_16x16x32_bf16(a0, bg0, accG[0][0], 0, 0, 0);
            accG[1][0] = __builtin_amdgcn_mfma_f32_16x16x32_bf16(a1, bg0, accG[1][0], 0, 0, 0);
            accG[0][1] = __builtin_amdgcn_mfma_f32_16x16x32_bf16(a0, bg1, accG[0][1], 0, 0, 0);
            accG[1][1] = __builtin_amdgcn_mfma_f32_16x16x32_bf16(a1, bg1, accG[1][1], 0, 0, 0);
            accF[0][0] = __builtin_amdgcn_mfma_f32_16x16x32_bf16(a0, bf0, accF[0][0], 0, 0, 0);
            accF[1][0] = __builtin_amdgcn_mfma_f32_16x16x32_bf16(a1, bf0, accF[1][0], 0, 0, 0);
            accF[0][1] = __builtin_amdgcn_mfma_f32_16x16x32_bf16(a0, bf1, accF[0][1], 0, 0, 0);
            accF[1][1] = __builtin_amdgcn_mfma_f32_16x16x32_bf16(a1, bf1, accF[1][1], 0, 0, 0);
        }

        LGKM0(); SBAR();   // all phase-1 tap reads done (tap0 about to be reused)

        // ---- res = sigmoid(G)*tanh(F) -> tap0 region (swizzled) ----
        #pragma unroll
        for (int rt = 0; rt < 2; ++rt)
            #pragma unroll
            for (int fc = 0; fc < 2; ++fc)
                #pragma unroll
                for (int i = 0; i < 4; ++i) {
                    const float g = accG[rt][fc][i];
                    const float f = accF[rt][fc][i];
                    const float sg = 1.0f / (1.0f + __expf(-g));
                    const float e2 = __expf(2.0f * f);
                    const float th = 1.0f - 2.0f / (e2 + 1.0f);
                    const float rr = sg * th;
                    const int row = rt * 16 + krow * 4 + i;
                    const int col = cg0 + fc * 16 + arow;
                    A_lds[(row << 8) + (((col << 1) ^ ((row & 7) << 4)) >> 1)] = f2bf(rr);
                }
        LGKM0(); SBAR();   // res visible (Wts chunks 24,25 still flying)

        // ---- phase 2: 8 chunks (out cols [64w, 64w+64) of thru||skip) ----
        f32x4 acc2[2][4];
        #pragma unroll
        for (int rt = 0; rt < 2; ++rt)
            #pragma unroll
            for (int fc = 0; fc < 4; ++fc)
                acc2[rt][fc] = (f32x4){0.f, 0.f, 0.f, 0.f};

        #pragma unroll
        for (int p = 0; p < 8; ++p) {
            if (p < 6) { stage_chunk(Wgf_k, Wts_k, B_lds, 26 + p, w, lane); VMW8(); }
            else if (p == 6) { VMW4(); }
            else { VMW0(); }
            const int aoff = ((p * 64 + krow * 16) ^ aswz) >> 1;
            const bf16x8 a0 = *(const bf16x8*)(A_lds + (arow << 8) + aoff);
            const bf16x8 a1 = *(const bf16x8*)(A_lds + ((16 + arow) << 8) + aoff);
            const unsigned short* Bw = B_lds + w * 6144 + ((24 + p) % 3) * 2048;
            const bf16x8 b0 = bread(Bw, arow, krow);
            const bf16x8 b1 = bread(Bw, 16 + arow, krow);
            const bf16x8 b2 = bread(Bw, 32 + arow, krow);
            const bf16x8 b3 = bread(Bw, 48 + arow, krow);
            acc2[0][0] = __builtin_amdgcn_mfma_f32_16x16x32_bf16(a0, b0, acc2[0][0], 0, 0, 0);
            acc2[1][0] = __builtin_amdgcn_mfma_f32_16x16x32_bf16(a1, b0, acc2[1][0], 0, 0, 0);
            acc2[0][1] = __builtin_amdgcn_mfma_f32_16x16x32_bf16(a0, b1, acc2[0][1], 0, 0, 0);
            acc2[1][1] = __builtin_amdgcn_mfma_f32_16x16x32_bf16(a1, b1, acc2[1][1], 0, 0, 0);
            acc2[0][2] = __builtin_amdgcn_mfma_f32_16x16x32_bf16(a0, b2, acc2[0][2], 0, 0, 0);
            acc2[1][2] = __builtin_amdgcn_mfma_f32_16x16x32_bf16(a1, b2, acc2[1][2], 0, 0, 0);
            acc2[0][3] = __builtin_amdgcn_mfma_f32_16x16x32_bf16(a0, b3, acc2[0][3], 0, 0, 0);
            acc2[1][3] = __builtin_amdgcn_mfma_f32_16x16x32_bf16(a1, b3, acc2[1][3], 0, 0, 0);
        }

        if (k < NL - 1) {
            // ---- epilogue: waves 0..3 H update; waves 4..7 S RMW ----
            if (w < 4) {
                #pragma unroll
                for (int rt = 0; rt < 2; ++rt)
                    #pragma unroll
                    for (int fc = 0; fc < 4; ++fc)
                        #pragma unroll
                        for (int i = 0; i < 4; ++i) {
                            const int row = rt * 16 + krow * 4 + i;
                            const int g   = ((j0 + row) << 8) + c0 + fc * 16 + arow;
                            const float v = hin[rt][fc][i] + acc2[rt][fc][i];
                            Hf_out[g] = v;
                            Hb_out[g] = f2bf(v);
                        }
            } else {
                #pragma unroll
                for (int rt = 0; rt < 2; ++rt)
                    #pragma unroll
                    for (int fc = 0; fc < 4; ++fc)
                        #pragma unroll
                        for (int i = 0; i < 4; ++i) {
                            const int row = rt * 16 + krow * 4 + i;
                            const int g   = ((j0 + row) << 8) + colb + fc * 16 + arow;
                            Sf[g] = hin[rt][fc][i] + acc2[rt][fc][i];
                        }
            }
            target += NBLK;
            grid_barrier(counter, target, tid);
            // swap H ping-pong
            const unsigned short* tb = Hb_in; Hb_in = Hb_out; Hb_out = (unsigned short*)tb;
            const float* tf = Hf_in; Hf_in = Hf_out; Hf_out = (float*)tf;
        } else {
            // ---- last layer: final S -> LDS tap0 (no global round-trip) ----
            LGKM0(); SBAR();   // everyone done reading tap0 (res)
            if (w >= 4) {
                #pragma unroll
                for (int rt = 0; rt < 2; ++rt)
                    #pragma unroll
                    for (int fc = 0; fc < 4; ++fc)
                        #pragma unroll
                        for (int i = 0; i < 4; ++i) {
                            const int row = rt * 16 + krow * 4 + i;
                            const int col = colb + fc * 16 + arow;
                            const float v = hin[rt][fc][i] + acc2[rt][fc][i];
                            A_lds[(row << 8) + (((col << 1) ^ ((row & 7) << 4)) >> 1)] = f2bf(v);
                        }
            }
            LGKM0(); SBAR();
        }
    }

    // ================= final: out = Wfb @ S^T + fbias =================
    {
        const int m0 = w * 32;   // co slice
        f32x4 facc[2][2];
        #pragma unroll
        for (int rt = 0; rt < 2; ++rt)
            #pragma unroll
            for (int fc = 0; fc < 2; ++fc)
                facc[rt][fc] = (f32x4){0.f, 0.f, 0.f, 0.f};

        #pragma unroll
        for (int kc = 0; kc < 8; ++kc) {
            const int koff = kc * 32 + krow * 8;
            const bf16x8 a0 = *(const bf16x8*)(Wfb + ((m0 + arow) << 8) + koff);
            const bf16x8 a1 = *(const bf16x8*)(Wfb + ((m0 + 16 + arow) << 8) + koff);
            const int aoff = ((kc * 64 + krow * 16) ^ aswz) >> 1;
            const bf16x8 b0 = *(const bf16x8*)(A_lds + (arow << 8) + aoff);
            const bf16x8 b1 = *(const bf16x8*)(A_lds + ((16 + arow) << 8) + aoff);
            facc[0][0] = __builtin_amdgcn_mfma_f32_16x16x32_bf16(a0, b0, facc[0][0], 0, 0, 0);
            facc[1][0] = __builtin_amdgcn_mfma_f32_16x16x32_bf16(a1, b0, facc[1][0], 0, 0, 0);
            facc[0][1] = __builtin_amdgcn_mfma_f32_16x16x32_bf16(a0, b1, facc[0][1], 0, 0, 0);
            facc[1][1] = __builtin_amdgcn_mfma_f32_16x16x32_bf16(a1, b1, facc[1][1], 0, 0, 0);
        }

        #pragma unroll
        for (int rt = 0; rt < 2; ++rt)
            #pragma unroll
            for (int fc = 0; fc < 2; ++fc)
                #pragma unroll
                for (int i = 0; i < 4; ++i) {
                    const int co = m0 + rt * 16 + krow * 4 + i;
                    const int jj = j0 + fc * 16 + arow;
                    out[((jj & 1) << 20) + (co << 12) + (jj >> 1)] = facc[rt][fc][i] + fbias[co];
                }
    }
}

// ---------------------------------------------------------------------------
extern "C" void kernel_launch(void* const* d_in, const int* in_sizes, int n_in,
                              void* d_out, int out_size, void* d_ws, size_t ws_size,
                              hipStream_t stream)
{
    const float* x       = (const float*)d_in[0];
    const float* init_w  = (const float*)d_in[1];
    const float* init_b  = (const float*)d_in[2];
    const float* iskip_w = (const float*)d_in[3];
    const float* iskip_b = (const float*)d_in[4];
    const float* gate_w  = (const float*)d_in[5];
    const float* gate_b  = (const float*)d_in[6];
    const float* feat_w  = (const float*)d_in[7];
    const float* feat_b  = (const float*)d_in[8];
    const float* skip_w  = (const float*)d_in[9];
    const float* thru_w  = (const float*)d_in[10];
    const float* final_w = (const float*)d_in[11];
    const float* final_b = (const float*)d_in[12];

    char* ws = (char*)d_ws;
    size_t off = 0;
    auto alloc = [&](size_t bytes) {
        void* p = ws + off;
        off += (bytes + 255) & ~(size_t)255;
        return p;
    };
    unsigned short* Wgf = (unsigned short*)alloc((size_t)NL * 3 * 512 * 256 * 2);
    unsigned short* Wts = (unsigned short*)alloc((size_t)NL * 512 * 256 * 2);
    unsigned short* Wib = (unsigned short*)alloc(256 * 256 * 2);
    unsigned short* Wfb = (unsigned short*)alloc(256 * 256 * 2);
    float*          Hf0 = (float*)alloc((size_t)TS * 256 * 4);
    float*          Hf1 = (float*)alloc((size_t)TS * 256 * 4);
    unsigned short* Hb0 = (unsigned short*)alloc((size_t)TS * 256 * 2);
    unsigned short* Hb1 = (unsigned short*)alloc((size_t)TS * 256 * 2);
    float*          Sf  = (float*)alloc((size_t)TS * 256 * 4);
    unsigned*       cnt = (unsigned*)alloc(256);

    hipMemsetAsync((void*)cnt, 0, 256, stream);
    prep_weights_kernel<<<2048, 256, 0, stream>>>(gate_w, feat_w, thru_w, skip_w,
                                                  iskip_w, final_w, Wgf, Wts, Wib, Wfb);
    wavenet_kernel<<<NBLK, 512, 0, stream>>>(
        x, init_w, init_b, Wib, iskip_b, Wgf, Wts, gate_b, feat_b,
        Wfb, final_b, Hf0, Hf1, Hb0, Hb1, Sf, (float*)d_out, cnt);
}

// Round 5
// 909.687 us; speedup vs baseline: 1.5088x; 1.5088x over previous
//
#include <hip/hip_runtime.h>

// WaveNet (nsynth batch-folding) on MI355X — persistent kernel, v5.
// Stream identity: batch-folding dilation == dilated conv over one 8192-sample
// stream, j = l*2 + n; fold-d taps at j +- 2d, zero-pad at stream ends.
//
// v5 key change: H (residual) and S (skip) fp32 masters live in REGISTERS for
// the whole net (fixed block/wave ownership). Only the bf16 mirror Hb touches
// global memory (halo exchange); the center tap is written directly into the
// next layer's A_lds at epilogue. Weight chunks 0,1 of layer k+1 are DMA'd
// before the grid barrier (weights immutable -> safe across acquire-inv).

#define TS 8192
#define NL 30
#define NBLK 256

typedef __attribute__((ext_vector_type(8))) short bf16x8;
typedef __attribute__((ext_vector_type(4))) float f32x4;

__device__ __forceinline__ unsigned short f2bf(float f) {
    union { float f; unsigned int u; } v; v.f = f;
    unsigned int u = v.u;
    u += 0x7fffu + ((u >> 16) & 1u);   // RNE
    return (unsigned short)(u >> 16);
}

__device__ __forceinline__ void gload_lds16(const void* g, void* l) {
    __builtin_amdgcn_global_load_lds(
        (const __attribute__((address_space(1))) void*)g,
        (__attribute__((address_space(3))) void*)l, 16, 0, 0);
}

#define VMW8()  asm volatile("s_waitcnt vmcnt(8)" ::: "memory")
#define VMW4()  asm volatile("s_waitcnt vmcnt(4)" ::: "memory")
#define VMW0()  asm volatile("s_waitcnt vmcnt(0)" ::: "memory")
#define LGKM0() asm volatile("s_waitcnt lgkmcnt(0)" ::: "memory")
#define SBAR()  __builtin_amdgcn_s_barrier()
#define MFMA16(a, b, c) __builtin_amdgcn_mfma_f32_16x16x32_bf16((a), (b), (c), 0, 0, 0)

__device__ __forceinline__ int swz_jb(int bid) {   // XCD-chunked j-tile map
    return ((bid & 7) << 5) | (bid >> 3);
}

// ---------------------------------------------------------------------------
// Weight prep: fp32 -> bf16 with layout transforms.
// Wgf[k][t][o][ci], o in [0,512): 0..255 gate, 256..511 feat (tap t split out)
// Wts[k][o][ci],    o in [0,512): 0..255 thru, 256..511 skip
// ---------------------------------------------------------------------------
__global__ void prep_weights_kernel(
    const float* __restrict__ gw, const float* __restrict__ fw,
    const float* __restrict__ tw, const float* __restrict__ sw,
    const float* __restrict__ iw, const float* __restrict__ fnw,
    unsigned short* __restrict__ Wgf, unsigned short* __restrict__ Wts,
    unsigned short* __restrict__ Wib, unsigned short* __restrict__ Wfb)
{
    const int idx = blockIdx.x * blockDim.x + threadIdx.x;
    const int stride = gridDim.x * blockDim.x;
    const int n_gf = NL * 3 * 512 * 256;
    for (int i = idx; i < n_gf; i += stride) {
        int ci = i & 255;
        int o  = (i >> 8) & 511;
        int r  = i >> 17;      // k*3 + t
        int t  = r % 3;
        int k  = r / 3;
        float v = (o < 256) ? gw[((k * 256 + o) * 256 + ci) * 3 + t]
                            : fw[((k * 256 + (o - 256)) * 256 + ci) * 3 + t];
        Wgf[i] = f2bf(v);
    }
    const int n_ts = NL * 512 * 256;
    for (int i = idx; i < n_ts; i += stride) {
        int ci = i & 255;
        int o  = (i >> 8) & 511;
        int k  = i >> 17;
        float v = (o < 256) ? tw[(k * 256 + o) * 256 + ci]
                            : sw[(k * 256 + (o - 256)) * 256 + ci];
        Wts[i] = f2bf(v);
    }
    for (int i = idx; i < 256 * 256; i += stride) Wib[i] = f2bf(iw[i]);
    for (int i = idx; i < 256 * 256; i += stride) Wfb[i] = f2bf(fnw[i]);
}

// ---------------------------------------------------------------------------
// Grid barrier: monotonic counter, release/acquire at agent scope.
// ---------------------------------------------------------------------------
__device__ __forceinline__ void grid_barrier(unsigned* cnt, unsigned target, int tid) {
    __syncthreads();
    if (tid == 0) {
        __hip_atomic_fetch_add(cnt, 1u, __ATOMIC_RELEASE, __HIP_MEMORY_SCOPE_AGENT);
        while (__hip_atomic_load(cnt, __ATOMIC_RELAXED, __HIP_MEMORY_SCOPE_AGENT) < target)
            __builtin_amdgcn_s_sleep(2);
        (void)__hip_atomic_load(cnt, __ATOMIC_ACQUIRE, __HIP_MEMORY_SCOPE_AGENT);
    }
    __syncthreads();
}

// ---------------------------------------------------------------------------
// B-chunk staging: chunk c in [0,32): c<24 -> Wgf tap t=c>>3, kc=c&7 (gate
// rows 32w.., feat rows 256+32w..); c>=24 -> Wts kc=c-24 (rows 64w..).
// Per-wave private slice, ring-3 x 4KB. Linear LDS dest; 16B-slot XOR
// pre-swizzle on the SOURCE address, undone at read (bread).
// ---------------------------------------------------------------------------
__device__ __forceinline__ void stage_chunk(
    const unsigned short* __restrict__ Wgf_k,
    const unsigned short* __restrict__ Wts_k,
    unsigned short* B_lds, int c, int w, int lane)
{
    const int buf  = c % 3;
    const int rsub = lane >> 2;                       // 0..15
    const int slot = (lane & 3) ^ ((lane >> 3) & 3);  // pre-swizzled src slot
    unsigned short* dst = B_lds + w * 6144 + buf * 2048;
    if (c < 24) {
        const int t = c >> 3, kc = c & 7;
        const unsigned short* Wb = Wgf_k + (t * 512 + 32 * w) * 256 + kc * 32 + slot * 8;
        #pragma unroll
        for (int q = 0; q < 4; ++q) {
            const int r_loc = q * 16 + rsub;                   // 0..63
            const int grow  = (q < 2) ? r_loc : (224 + r_loc); // feat at +256
            gload_lds16(Wb + grow * 256, dst + q * 512);
        }
    } else {
        const int kc = c - 24;
        const unsigned short* Wb = Wts_k + (64 * w) * 256 + kc * 32 + slot * 8;
        #pragma unroll
        for (int q = 0; q < 4; ++q)
            gload_lds16(Wb + (q * 16 + rsub) * 256, dst + q * 512);
    }
}

// read B fragment: local row r (0..63), k-quarter krow (0..3)
__device__ __forceinline__ bf16x8 bread(const unsigned short* Bw, int r, int krow)
{
    const int slot = krow ^ ((r >> 1) & 3);
    return *(const bf16x8*)(Bw + r * 32 + slot * 8);
}

// ---------------------------------------------------------------------------
__global__ __launch_bounds__(512, 2)
void wavenet_kernel(const float* __restrict__ x,
                    const float* __restrict__ init_w,
                    const float* __restrict__ init_b,
                    const unsigned short* __restrict__ Wib,
                    const float* __restrict__ ib,
                    const unsigned short* __restrict__ Wgf,
                    const unsigned short* __restrict__ Wts,
                    const float* __restrict__ gbA,
                    const float* __restrict__ fbA,
                    const unsigned short* __restrict__ Wfb,
                    const float* __restrict__ fbias,
                    unsigned short* __restrict__ Hb0,
                    unsigned short* __restrict__ Hb1,
                    float* __restrict__ out,
                    unsigned* __restrict__ counter)
{
    __shared__ __align__(16) unsigned short A_lds[3 * 32 * 256];   // 48 KB
    __shared__ __align__(16) unsigned short B_lds[8 * 3 * 2048];   // 96 KB

    const int tid  = threadIdx.x;
    const int lane = tid & 63;
    const int w    = tid >> 6;
    const int j0   = swz_jb(blockIdx.x) * 32;
    const int arow = lane & 15;
    const int krow = lane >> 4;
    const int aswz = (arow & 7) << 4;
    const int cg0  = w * 32;
    const int c0   = w * 64;          // H cols (w<4) base
    const int cs0  = (w - 4) * 64;    // S cols (w>=4) base

    // persistent fp32 master: H cols [c0,c0+64) for waves 0-3,
    //                         S cols [cs0,cs0+64) for waves 4-7
    f32x4 state[2][4];

    // ================= init conv -> state (waves 0-3), Hb0 + LDS tap1 ======
    if (w < 4) {
        #pragma unroll
        for (int rt = 0; rt < 2; ++rt)
            #pragma unroll
            for (int fc = 0; fc < 4; ++fc) {
                #pragma unroll
                for (int i = 0; i < 4; ++i) {
                    const int row = rt * 16 + krow * 4 + i;
                    const int col = c0 + fc * 16 + arow;
                    const int j   = j0 + row;
                    float acc = init_b[col];
                    #pragma unroll
                    for (int t = 0; t < 3; ++t) {
                        const int i2 = j + 2 * t - 2;
                        if (i2 >= 0 && i2 < TS)
                            acc += init_w[col * 3 + t] * x[(i2 & 1) * 4096 + (i2 >> 1)];
                    }
                    state[rt][fc][i] = acc;
                    const unsigned short hb = f2bf(acc);
                    Hb0[(j << 8) + col] = hb;
                    A_lds[((32 + row) << 8) + (((col << 1) ^ ((row & 7) << 4)) >> 1)] = hb;
                }
            }
    }
    LGKM0(); SBAR();   // H0 (bf16) visible in tap1

    // ================= iskip -> state (waves 4-7) ==========================
    if (w >= 4) {
        #pragma unroll
        for (int rt = 0; rt < 2; ++rt)
            #pragma unroll
            for (int fc = 0; fc < 4; ++fc) {
                const float b = ib[cs0 + fc * 16 + arow];
                state[rt][fc] = (f32x4){b, b, b, b};
            }
        #pragma unroll
        for (int kc = 0; kc < 8; ++kc) {
            const int aoff = ((kc * 64 + krow * 16) ^ aswz) >> 1;
            const bf16x8 a0 = *(const bf16x8*)(A_lds + ((32 + arow) << 8) + aoff);
            const bf16x8 a1 = *(const bf16x8*)(A_lds + ((48 + arow) << 8) + aoff);
            const int koff = kc * 32 + krow * 8;
            #pragma unroll
            for (int fc = 0; fc < 4; ++fc) {
                const bf16x8 bb = *(const bf16x8*)(Wib + ((cs0 + fc * 16 + arow) << 8) + koff);
                state[0][fc] = MFMA16(a0, bb, state[0][fc]);
                state[1][fc] = MFMA16(a1, bb, state[1][fc]);
            }
        }
    }

    // pre-stage layer-0 weight chunks 0,1 (fly across the grid barrier)
    stage_chunk(Wgf, Wts, B_lds, 0, w, lane);
    stage_chunk(Wgf, Wts, B_lds, 1, w, lane);

    unsigned target = NBLK;
    grid_barrier(counter, target, tid);

    const unsigned short* Hb_in = Hb0;
    unsigned short*       Hb_out = Hb1;

    // ============================ layer loop ================================
    for (int k = 0; k < NL; ++k) {
        const int d = 2 << (k % 10);   // stream dilation = 2 * 2^(k%10)
        const unsigned short* Wgf_k = Wgf + (size_t)k * 3 * 512 * 256;
        const unsigned short* Wts_k = Wts + (size_t)k * 512 * 256;
        const float gv0 = gbA[k * 256 + cg0 + arow];
        const float gv1 = gbA[k * 256 + cg0 + 16 + arow];
        const float fv0 = fbA[k * 256 + cg0 + arow];
        const float fv1 = fbA[k * 256 + cg0 + 16 + arow];

        // ---- A-stage: taps 0 and 2 only (center tap already in tap1) ----
        #pragma unroll
        for (int q = 0; q < 4; ++q) {
            const int cc  = tid + q * 512;
            const int c16 = cc & 31;
            const int m   = (cc >> 5) & 31;
            const int t   = (cc >> 10) << 1;            // 0 or 2
            const int r   = j0 + m + (t - 1) * d;
            uint4 v = make_uint4(0u, 0u, 0u, 0u);
            if (r >= 0 && r < TS)
                v = *(const uint4*)(Hb_in + (r << 8) + (c16 << 3));
            const int sb = (c16 << 4) ^ ((m & 7) << 4);
            *(uint4*)(A_lds + ((t * 32 + m) << 8) + (sb >> 1)) = v;
        }
        LGKM0(); SBAR();   // A complete

        // ---- phase 1: 24 chunks, ring-3, depth-2 counted vmcnt ----
        f32x4 accG[2][2], accF[2][2];
        accG[0][0] = (f32x4){gv0, gv0, gv0, gv0};
        accG[1][0] = accG[0][0];
        accG[0][1] = (f32x4){gv1, gv1, gv1, gv1};
        accG[1][1] = accG[0][1];
        accF[0][0] = (f32x4){fv0, fv0, fv0, fv0};
        accF[1][0] = accF[0][0];
        accF[0][1] = (f32x4){fv1, fv1, fv1, fv1};
        accF[1][1] = accF[0][1];

        #pragma unroll
        for (int c = 0; c < 24; ++c) {
            stage_chunk(Wgf_k, Wts_k, B_lds, c + 2, w, lane);
            VMW8();                                     // chunk c landed
            const int t = c >> 3, kc = c & 7;
            const int aoff = ((kc * 64 + krow * 16) ^ aswz) >> 1;
            const unsigned short* At = A_lds + ((t * 32 + arow) << 8);
            const bf16x8 a0 = *(const bf16x8*)(At + aoff);
            const bf16x8 a1 = *(const bf16x8*)(At + (16 << 8) + aoff);
            const unsigned short* Bw = B_lds + w * 6144 + (c % 3) * 2048;
            const bf16x8 bg0 = bread(Bw, arow, krow);
            const bf16x8 bg1 = bread(Bw, 16 + arow, krow);
            const bf16x8 bf0 = bread(Bw, 32 + arow, krow);
            const bf16x8 bf1 = bread(Bw, 48 + arow, krow);
            accG[0][0] = MFMA16(a0, bg0, accG[0][0]);
            accG[1][0] = MFMA16(a1, bg0, accG[1][0]);
            accG[0][1] = MFMA16(a0, bg1, accG[0][1]);
            accG[1][1] = MFMA16(a1, bg1, accG[1][1]);
            accF[0][0] = MFMA16(a0, bf0, accF[0][0]);
            accF[1][0] = MFMA16(a1, bf0, accF[1][0]);
            accF[0][1] = MFMA16(a0, bf1, accF[0][1]);
            accF[1][1] = MFMA16(a1, bf1, accF[1][1]);
        }

        LGKM0(); SBAR();   // phase-1 LDS reads done (tap0 reused for res)

        // ---- res = sigmoid(G)*tanh(F) -> tap0 (swizzled) ----
        #pragma unroll
        for (int rt = 0; rt < 2; ++rt)
            #pragma unroll
            for (int fc = 0; fc < 2; ++fc)
                #pragma unroll
                for (int i = 0; i < 4; ++i) {
                    const float g = accG[rt][fc][i];
                    const float f = accF[rt][fc][i];
                    const float sg = 1.0f / (1.0f + __expf(-g));
                    const float e2 = __expf(2.0f * f);
                    const float th = 1.0f - 2.0f / (e2 + 1.0f);
                    const float rr = sg * th;
                    const int row = rt * 16 + krow * 4 + i;
                    const int col = cg0 + fc * 16 + arow;
                    A_lds[(row << 8) + (((col << 1) ^ ((row & 7) << 4)) >> 1)] = f2bf(rr);
                }
        LGKM0(); SBAR();   // res visible (chunks 24,25 still flying)

        // ---- phase 2: 8 chunks; acc starts from persistent state ----
        f32x4 acc2[2][4];
        #pragma unroll
        for (int rt = 0; rt < 2; ++rt)
            #pragma unroll
            for (int fc = 0; fc < 4; ++fc)
                acc2[rt][fc] = state[rt][fc];

        #pragma unroll
        for (int p = 0; p < 8; ++p) {
            if (p < 6) { stage_chunk(Wgf_k, Wts_k, B_lds, 26 + p, w, lane); VMW8(); }
            else if (p == 6) { VMW4(); }
            else { VMW0(); }
            const int aoff = ((p * 64 + krow * 16) ^ aswz) >> 1;
            const bf16x8 a0 = *(const bf16x8*)(A_lds + (arow << 8) + aoff);
            const bf16x8 a1 = *(const bf16x8*)(A_lds + ((16 + arow) << 8) + aoff);
            const unsigned short* Bw = B_lds + w * 6144 + ((24 + p) % 3) * 2048;
            const bf16x8 b0 = bread(Bw, arow, krow);
            const bf16x8 b1 = bread(Bw, 16 + arow, krow);
            const bf16x8 b2 = bread(Bw, 32 + arow, krow);
            const bf16x8 b3 = bread(Bw, 48 + arow, krow);
            acc2[0][0] = MFMA16(a0, b0, acc2[0][0]);
            acc2[1][0] = MFMA16(a1, b0, acc2[1][0]);
            acc2[0][1] = MFMA16(a0, b1, acc2[0][1]);
            acc2[1][1] = MFMA16(a1, b1, acc2[1][1]);
            acc2[0][2] = MFMA16(a0, b2, acc2[0][2]);
            acc2[1][2] = MFMA16(a1, b2, acc2[1][2]);
            acc2[0][3] = MFMA16(a0, b3, acc2[0][3]);
            acc2[1][3] = MFMA16(a1, b3, acc2[1][3]);
        }

        // ---- state update (registers only) ----
        #pragma unroll
        for (int rt = 0; rt < 2; ++rt)
            #pragma unroll
            for (int fc = 0; fc < 4; ++fc)
                state[rt][fc] = acc2[rt][fc];

        if (k < NL - 1) {
            // waves 0-3: publish bf16 H to global (halo) + LDS tap1 (center)
            if (w < 4) {
                #pragma unroll
                for (int rt = 0; rt < 2; ++rt)
                    #pragma unroll
                    for (int fc = 0; fc < 4; ++fc)
                        #pragma unroll
                        for (int i = 0; i < 4; ++i) {
                            const int row = rt * 16 + krow * 4 + i;
                            const int col = c0 + fc * 16 + arow;
                            const unsigned short hb = f2bf(state[rt][fc][i]);
                            Hb_out[((j0 + row) << 8) + col] = hb;
                            A_lds[((32 + row) << 8) + (((col << 1) ^ ((row & 7) << 4)) >> 1)] = hb;
                        }
            }
            // pre-stage next layer's chunks 0,1 (slots free; fly across barrier)
            stage_chunk(Wgf_k + 3 * 512 * 256, Wts_k + 512 * 256, B_lds, 0, w, lane);
            stage_chunk(Wgf_k + 3 * 512 * 256, Wts_k + 512 * 256, B_lds, 1, w, lane);

            target += NBLK;
            grid_barrier(counter, target, tid);

            unsigned short* tmp = (unsigned short*)Hb_in;
            Hb_in = Hb_out; Hb_out = tmp;
        } else {
            // last layer: S (waves 4-7) -> tap0 bf16 for the final GEMM
            SBAR();   // all phase-2 tap0 reads done
            if (w >= 4) {
                #pragma unroll
                for (int rt = 0; rt < 2; ++rt)
                    #pragma unroll
                    for (int fc = 0; fc < 4; ++fc)
                        #pragma unroll
                        for (int i = 0; i < 4; ++i) {
                            const int row = rt * 16 + krow * 4 + i;
                            const int col = cs0 + fc * 16 + arow;
                            A_lds[(row << 8) + (((col << 1) ^ ((row & 7) << 4)) >> 1)] =
                                f2bf(state[rt][fc][i]);
                        }
            }
            LGKM0(); SBAR();
        }
    }

    // ================= final: out = Wfb @ S^T + fbias =======================
    {
        const int m0 = w * 32;   // co slice
        f32x4 facc[2][2];
        #pragma unroll
        for (int rt = 0; rt < 2; ++rt)
            #pragma unroll
            for (int fc = 0; fc < 2; ++fc)
                facc[rt][fc] = (f32x4){0.f, 0.f, 0.f, 0.f};

        #pragma unroll
        for (int kc = 0; kc < 8; ++kc) {
            const int koff = kc * 32 + krow * 8;
            const bf16x8 a0 = *(const bf16x8*)(Wfb + ((m0 + arow) << 8) + koff);
            const bf16x8 a1 = *(const bf16x8*)(Wfb + ((m0 + 16 + arow) << 8) + koff);
            const int aoff = ((kc * 64 + krow * 16) ^ aswz) >> 1;
            const bf16x8 b0 = *(const bf16x8*)(A_lds + (arow << 8) + aoff);
            const bf16x8 b1 = *(const bf16x8*)(A_lds + ((16 + arow) << 8) + aoff);
            facc[0][0] = MFMA16(a0, b0, facc[0][0]);
            facc[1][0] = MFMA16(a1, b0, facc[1][0]);
            facc[0][1] = MFMA16(a0, b1, facc[0][1]);
            facc[1][1] = MFMA16(a1, b1, facc[1][1]);
        }

        #pragma unroll
        for (int rt = 0; rt < 2; ++rt)
            #pragma unroll
            for (int fc = 0; fc < 2; ++fc)
                #pragma unroll
                for (int i = 0; i < 4; ++i) {
                    const int co = m0 + rt * 16 + krow * 4 + i;
                    const int jj = j0 + fc * 16 + arow;
                    out[((jj & 1) << 20) + (co << 12) + (jj >> 1)] = facc[rt][fc][i] + fbias[co];
                }
    }
}

// ---------------------------------------------------------------------------
extern "C" void kernel_launch(void* const* d_in, const int* in_sizes, int n_in,
                              void* d_out, int out_size, void* d_ws, size_t ws_size,
                              hipStream_t stream)
{
    const float* x       = (const float*)d_in[0];
    const float* init_w  = (const float*)d_in[1];
    const float* init_b  = (const float*)d_in[2];
    const float* iskip_w = (const float*)d_in[3];
    const float* iskip_b = (const float*)d_in[4];
    const float* gate_w  = (const float*)d_in[5];
    const float* gate_b  = (const float*)d_in[6];
    const float* feat_w  = (const float*)d_in[7];
    const float* feat_b  = (const float*)d_in[8];
    const float* skip_w  = (const float*)d_in[9];
    const float* thru_w  = (const float*)d_in[10];
    const float* final_w = (const float*)d_in[11];
    const float* final_b = (const float*)d_in[12];

    char* ws = (char*)d_ws;
    size_t off = 0;
    auto alloc = [&](size_t bytes) {
        void* p = ws + off;
        off += (bytes + 255) & ~(size_t)255;
        return p;
    };
    unsigned short* Wgf = (unsigned short*)alloc((size_t)NL * 3 * 512 * 256 * 2);
    unsigned short* Wts = (unsigned short*)alloc((size_t)NL * 512 * 256 * 2);
    unsigned short* Wib = (unsigned short*)alloc(256 * 256 * 2);
    unsigned short* Wfb = (unsigned short*)alloc(256 * 256 * 2);
    unsigned short* Hb0 = (unsigned short*)alloc((size_t)TS * 256 * 2);
    unsigned short* Hb1 = (unsigned short*)alloc((size_t)TS * 256 * 2);
    unsigned*       cnt = (unsigned*)alloc(256);

    hipMemsetAsync((void*)cnt, 0, 256, stream);
    prep_weights_kernel<<<2048, 256, 0, stream>>>(gate_w, feat_w, thru_w, skip_w,
                                                  iskip_w, final_w, Wgf, Wts, Wib, Wfb);
    wavenet_kernel<<<NBLK, 512, 0, stream>>>(
        x, init_w, init_b, Wib, iskip_b, Wgf, Wts, gate_b, feat_b,
        Wfb, final_b, Hb0, Hb1, (float*)d_out, cnt);
}